// Round 3
// baseline (116.518 us; speedup 1.0000x reference)
//
#include <hip/hip_runtime.h>
#include <stdint.h>

// Problem constants (fixed by the reference)
#define BQ    32     // batch
#define NSUB  512    // subjects per image
#define NDET  1024   // subjects + objects
#define NCLS  30     // labels 0..29
#define KSLOT 30     // 15 subject + 15 object output slots
#define BCAP  96     // max active boxes per (image,class); mean ~27

#pragma clang fp contract(off)

typedef unsigned long long u64;

// ---------------- Kernel 1: per-image box max (+ zero done ctr) ------------
// Global max over ALL boxes = max over the 32 per-image maxes (fmax assoc.).
// Must precede NMS so the per-class offset arithmetic is bit-exact vs ref.
__global__ __launch_bounds__(512) void pmax_kernel(
    const float* __restrict__ sb, const float* __restrict__ ob,
    float* __restrict__ pmax, int* __restrict__ done)
{
    const int b = blockIdx.x, t = threadIdx.x;
    const int lane = t & 63, w = t >> 6;
    __shared__ float wred[8];
    const float4* sb4 = (const float4*)sb;
    const float4* ob4 = (const float4*)ob;
    float4 a  = sb4[(size_t)b * NSUB + t];
    float4 c4 = ob4[(size_t)b * NSUB + t];
    float m = fmaxf(fmaxf(fmaxf(a.x, a.y), fmaxf(a.z, a.w)),
                    fmaxf(fmaxf(c4.x, c4.y), fmaxf(c4.z, c4.w)));
    for (int off = 32; off; off >>= 1) m = fmaxf(m, __shfl_xor(m, off));
    if (lane == 0) wred[w] = m;
    __syncthreads();
    if (t == 0) {
        float mm = wred[0];
        for (int i = 1; i < 8; ++i) mm = fmaxf(mm, wred[i]);
        pmax[b] = mm;
        done[b] = 0;                       // ws is poisoned; reset per launch
    }
}

// ------- Kernel 2: fused scan+bucket + NMS + last-arriver select -----------
// One wave per (class,image). Each block rebuilds its class bucket by scanning
// the image's 1024 detections (register-preloaded, ballot-compacted in index
// order -> deterministic, same key set as the verified atomic bucketing).
// NMS decision arithmetic is verbatim from the verified kernel. Kept lists go
// to ws; the 30th block per image (device-scope atomic) runs the select.
__global__ __launch_bounds__(64) void nms_fused_kernel(
    const float* __restrict__ sb, const float* __restrict__ ss,
    const int*   __restrict__ sl,
    const float* __restrict__ ob, const float* __restrict__ os,
    const int*   __restrict__ ol,
    const float* __restrict__ pmax, int* __restrict__ done,
    u64* __restrict__ subk, u64* __restrict__ objk,
    float4* __restrict__ subb, float4* __restrict__ objb,
    float* __restrict__ out)
{
#pragma clang fp contract(off)
    const int c    = blockIdx.x;      // class 0..29
    const int b    = blockIdx.y;      // image
    const int lane = threadIdx.x;

    __shared__ u64    ukey[BCAP];     // unsorted bucket keys (index order)
    __shared__ float4 ubox[BCAP];     // unsorted bucket boxes
    __shared__ u64    skey[BCAP];     // rank-sorted keys
    __shared__ float4 sbox[BCAP];     // rank-sorted boxes
    __shared__ float4 selbx[NCLS * 15]; // select-phase staged boxes (last blk)

    const float4* sb4 = (const float4*)sb;
    const float4* ob4 = (const float4*)ob;

    // ---- global max_coord: reduce the 32 per-image maxes ----
    float pv = pmax[lane & 31];
    for (int off = 32; off; off >>= 1) pv = fmaxf(pv, __shfl_xor(pv, off));
    const float mco  = pv + 1.0f;                    // (max_coord + 1.0)
    const float offc = (float)c * mco;

    // ---- scan this image's 1024 dets: preload ALL into registers ----------
    float4 rbx[16]; float rsc[16]; int rlb[16];
    #pragma unroll
    for (int it = 0; it < 16; ++it) {
        int i = it * 64 + lane;                      // concat det index
        if (it < 8) {                                // subjects (uniform branch)
            rbx[it] = sb4[(size_t)b * NSUB + i];
            rsc[it] = ss[b * NSUB + i];
            rlb[it] = sl[b * NSUB + i];
        } else {                                     // objects
            int j = i - NSUB;
            rbx[it] = ob4[(size_t)b * NSUB + j];
            rsc[it] = os[b * NSUB + j];
            rlb[it] = ol[b * NSUB + j];
        }
    }
    // ---- ballot-compact actives of class c into LDS (index order) ---------
    int cbase = 0;
    #pragma unroll
    for (int it = 0; it < 16; ++it) {
        int i = it * 64 + lane;
        bool match = (rsc[it] >= 0.2f) && (rlb[it] == c);
        u64 bal = __ballot(match);
        if (match) {
            int pos = cbase + (int)__popcll(bal & ((1ull << lane) - 1ull));
            if (pos < BCAP) {
                // key = (score bits, 1023 - concat idx): unique, desc order ==
                // stable sort by -score (lower original idx wins ties)
                ukey[pos] = ((u64)__float_as_uint(rsc[it]) << 32) | (u64)(1023 - i);
                ubox[pos] = rbx[it];
            }
        }
        cbase += (int)__popcll(bal);
    }
    const int cnt = (cbase < BCAP) ? cbase : BCAP;
    __threadfence_block();                           // in-wave LDS RAW

    // ---- speculative LDS picks (masked by cnt below; garbage safe) --------
    u64    K1 = ukey[lane];
    float4 B1 = ubox[lane];
    u64 K2 = 0; float4 B2 = make_float4(0.f, 0.f, 0.f, 0.f);
    if (lane < BCAP - 64) { K2 = ukey[64 + lane]; B2 = ubox[64 + lane]; }

    // ---- rank-sort desc by unique key; scatter key AND box by rank --------
    {
        int r = 0;
        for (int l = 0; l < cnt; ++l) r += (ukey[l] > K1) ? 1 : 0;
        if (lane < cnt) { skey[r] = K1; sbox[r] = B1; }
    }
    if (cnt > 64) {                                  // rare second chunk
        int e = 64 + lane;
        int r = 0;
        for (int l = 0; l < cnt; ++l) r += (ukey[l] > K2) ? 1 : 0;
        if (e < cnt) { skey[r] = K2; sbox[r] = B2; }
    }
    __threadfence_block();

    // ---- sorted entries now in LDS ----
    const int  lim1  = (cnt < 64) ? cnt : 64;
    const bool have1 = (lane < lim1);
    u64 SK1 = have1 ? skey[lane] : 0;
    int idx1 = 1023 - (int)(unsigned)(SK1 & 0xffffffffull);
    float4 bj1 = have1 ? sbox[lane] : make_float4(0.f, 0.f, 0.f, 0.f);
    const bool have2 = (64 + lane) < cnt;
    u64 SK2 = 0; int idx2 = 0; float4 bj2 = make_float4(0.f, 0.f, 0.f, 0.f);
    if (cnt > 64) {
        SK2 = have2 ? skey[64 + lane] : 0;
        idx2 = 1023 - (int)(unsigned)(SK2 & 0xffffffffull);
        if (have2) bj2 = sbox[64 + lane];
    }

    // ---- chunk A: overlap masks + ballot resolve (verbatim decision body) --
    float j0 = bj1.x + offc, j1 = bj1.y + offc;
    float j2v = bj1.z + offc, j3 = bj1.w + offc;
    float aj = (j2v - j0) * (j3 - j1);
    u64 ov = 0;
    for (int l = 0; l < lim1; ++l) {
        float4 bl = sbox[l];
        float i0 = bl.x + offc, i1 = bl.y + offc;
        float i2 = bl.z + offc, i3 = bl.w + offc;
        float ai = (i2 - i0) * (i3 - i1);
        if (have1 && l < lane) {
            float ltx = fmaxf(i0, j0), lty = fmaxf(i1, j1);
            float rbx_ = fminf(i2, j2v), rby = fminf(i3, j3);
            float wx = fmaxf(rbx_ - ltx, 0.0f), wy = fmaxf(rby - lty, 0.0f);
            float inter = wx * wy;
            float iou = inter / ((ai + aj) - inter);
            if (iou > 0.5f) ov |= (1ull << l);
        }
    }
    bool sup1 = !have1;
    for (int l = 0; l < lim1; ++l) {     // invariant: final for lanes <= l
        u64 bal = __ballot(sup1);
        if (!((bal >> l) & 1ull)) sup1 = sup1 || (((ov >> l) & 1ull) != 0ull);
    }
    const bool kept1 = have1 && !sup1;
    const u64 keptA = __ballot(kept1);

    // ---- chunk B (rare): entries 64..cnt-1 ----
    bool kept2 = false;
    if (cnt > 64) {
        float k0 = bj2.x + offc, k1 = bj2.y + offc;
        float k2 = bj2.z + offc, k3 = bj2.w + offc;
        float ak = (k2 - k0) * (k3 - k1);
        bool sup2 = !have2;
        for (int l = 0; l < 64; ++l) {               // vs kept chunk-A entries
            if ((keptA >> l) & 1ull) {
                float4 bl = sbox[l];
                float i0 = bl.x + offc, i1 = bl.y + offc;
                float i2 = bl.z + offc, i3 = bl.w + offc;
                float ai = (i2 - i0) * (i3 - i1);
                if (!sup2) {
                    float ltx = fmaxf(i0, k0), lty = fmaxf(i1, k1);
                    float rbx_ = fminf(i2, k2), rby = fminf(i3, k3);
                    float wx = fmaxf(rbx_ - ltx, 0.0f), wy = fmaxf(rby - lty, 0.0f);
                    float inter = wx * wy;
                    float iou = inter / ((ai + ak) - inter);
                    if (iou > 0.5f) sup2 = true;
                }
            }
        }
        u64 ov2 = 0;
        const int lim2 = cnt - 64;
        for (int l = 0; l < lim2; ++l) {
            float4 bl = sbox[64 + l];
            float i0 = bl.x + offc, i1 = bl.y + offc;
            float i2 = bl.z + offc, i3 = bl.w + offc;
            float ai = (i2 - i0) * (i3 - i1);
            if (have2 && l < lane) {
                float ltx = fmaxf(i0, k0), lty = fmaxf(i1, k1);
                float rbx_ = fminf(i2, k2), rby = fminf(i3, k3);
                float wx = fmaxf(rbx_ - ltx, 0.0f), wy = fmaxf(rby - lty, 0.0f);
                float inter = wx * wy;
                float iou = inter / ((ai + ak) - inter);
                if (iou > 0.5f) ov2 |= (1ull << l);
            }
        }
        for (int l = 0; l < lim2; ++l) {
            u64 bal = __ballot(sup2);
            if (!((bal >> l) & 1ull)) sup2 = sup2 || (((ov2 >> l) & 1ull) != 0ull);
        }
        kept2 = have2 && !sup2;
    }

    // ---- write first <=15 kept subject / object (key, box) for this class --
    const size_t base = (size_t)b * NCLS + c;
    const bool s1 = kept1 && (idx1 < NSUB), o1 = kept1 && (idx1 >= NSUB);
    const bool s2 = kept2 && (idx2 < NSUB), o2 = kept2 && (idx2 >= NSUB);
    const u64 mS1 = __ballot(s1), mS2 = __ballot(s2);
    const u64 mO1 = __ballot(o1), mO2 = __ballot(o2);
    const u64 ltm = (1ull << lane) - 1ull;
    u64*    subp = subk + base * 15;   float4* sbbp = subb + base * 15;
    u64*    objp = objk + base * 15;   float4* obbp = objb + base * 15;
    if (s1) { int p = (int)__popcll(mS1 & ltm); if (p < 15) { subp[p] = SK1; sbbp[p] = bj1; } }
    if (s2) { int p = (int)__popcll(mS1) + (int)__popcll(mS2 & ltm); if (p < 15) { subp[p] = SK2; sbbp[p] = bj2; } }
    if (o1) { int p = (int)__popcll(mO1 & ltm); if (p < 15) { objp[p] = SK1; obbp[p] = bj1; } }
    if (o2) { int p = (int)__popcll(mO1) + (int)__popcll(mO2 & ltm); if (p < 15) { objp[p] = SK2; obbp[p] = bj2; } }
    int tS = (int)(__popcll(mS1) + __popcll(mS2)); if (tS > 15) tS = 15;
    int tO = (int)(__popcll(mO1) + __popcll(mO2)); if (tO > 15) tO = 15;
    if (lane >= tS && lane < 15) subp[lane] = 0;   // key 0 = empty slot
    if (lane >= tO && lane < 15) objp[lane] = 0;   // (tail boxes never read)

    // ---- last-arriver: 30th block of this image runs the select -----------
    __threadfence();                               // release kept-list stores
    int prev = 0;
    if (lane == 0) prev = atomicAdd(&done[b], 1); // device-scope (guide G12)
    prev = __shfl(prev, 0);
    if (prev != NCLS - 1) return;
    __threadfence();                               // acquire: invalidate caches

    float* outB = out;                    // [32][30][4]
    float* outS = out + BQ * KSLOT * 4;   // 3840
    float* outL = outS + BQ * KSLOT;      // 4800
    float* outN = outL + BQ * KSLOT;      // 5760
    float* outV = outN + BQ;              // 5792

    for (int side = 0; side < 2; ++side) {
        const u64*    src  = (side ? objk : subk) + (size_t)b * NCLS * 15;
        const float4* srcb = (side ? objb : subb) + (size_t)b * NCLS * 15;

        u64 kk[8];                        // strided: lane + 64*i (covers 450)
        #pragma unroll
        for (int i = 0; i < 8; ++i) {
            int p = lane + 64 * i;
            kk[i] = (p < NCLS * 15) ? src[p] : 0;
        }
        for (int p = lane; p < NCLS * 15; p += 64) selbx[p] = srcb[p];
        __threadfence_block();            // in-wave LDS RAW

        int nvalid = 0;
        for (int r = 0; r < 15; ++r) {    // 15 argmax rounds (LDS/regs only)
            u64 lm = 0;
            #pragma unroll
            for (int i = 0; i < 8; ++i) lm = (kk[i] > lm) ? kk[i] : lm;
            u64 gm = lm;
            for (int off = 32; off; off >>= 1) {
                u64 o = __shfl_xor(gm, off);
                if (o > gm) gm = o;
            }
            int p = b * KSLOT + (side ? (15 + r) : r);
            if (gm == 0) {                // no more candidates: empty slot
                if (lane == 0) {
                    *(float4*)(outB + (size_t)p * 4) = make_float4(0.f, 0.f, 0.f, 0.f);
                    outS[p] = 0.0f; outL[p] = -1.0f; outV[p] = 0.0f;
                }
            } else {
                u64 win = __ballot(lm == gm);      // keys unique if nonzero
                int wl = (int)__ffsll(win) - 1;
                if (lane == wl) {
                    int sp = 0;                    // slot of gm (static idx)
                    #pragma unroll
                    for (int i = 0; i < 8; ++i) if (kk[i] == gm) sp = lane + 64 * i;
                    #pragma unroll
                    for (int i = 0; i < 8; ++i) if (kk[i] == gm) kk[i] = 0;  // consume
                    float4 bx = selbx[sp];         // box carried through NMS
                    float score = __uint_as_float((unsigned)(gm >> 32));     // exact
                    int cls = sp / 15;             // label = bucket class
                    *(float4*)(outB + (size_t)p * 4) = bx;
                    outS[p] = score;
                    outL[p] = (float)cls;
                    outV[p] = 1.0f;
                }
                nvalid++;                          // uniform across lanes
            }
        }
        if (side == 0 && lane == 0) outN[b] = (float)nvalid; // = min(total_s,15)
        __threadfence_block();            // selbx reused by side 1
    }
}

extern "C" void kernel_launch(void* const* d_in, const int* in_sizes, int n_in,
                              void* d_out, int out_size, void* d_ws, size_t ws_size,
                              hipStream_t stream) {
    const float* sb = (const float*)d_in[0];
    const float* ss = (const float*)d_in[1];
    const int*   sl = (const int*)d_in[2];
    const float* ob = (const float*)d_in[3];
    const float* os = (const float*)d_in[4];
    const int*   ol = (const int*)d_in[5];

    // ws layout (~0.7 MB; offsets 256-aligned)
    float*  pmax = (float*)d_ws;                      // [32]
    int*    done = (int*)((char*)d_ws + 256);         // [32] last-arriver ctr
    u64*    subk = (u64*)((char*)d_ws + 4096);        // [32][30][15] 115200 B
    u64*    objk = (u64*)((char*)d_ws + 119296);      // [32][30][15]
    float4* subb = (float4*)((char*)d_ws + 234496);   // [32][30][15] 230400 B
    float4* objb = (float4*)((char*)d_ws + 464896);   // [32][30][15]

    pmax_kernel<<<dim3(BQ), dim3(512), 0, stream>>>(sb, ob, pmax, done);
    nms_fused_kernel<<<dim3(NCLS, BQ), dim3(64), 0, stream>>>(
        sb, ss, sl, ob, os, ol, pmax, done, subk, objk, subb, objb,
        (float*)d_out);
}

// Round 4
// 82.199 us; speedup vs baseline: 1.4175x; 1.4175x over previous
//
#include <hip/hip_runtime.h>
#include <stdint.h>

// Problem constants (fixed by the reference)
#define BQ    32     // batch
#define NSUB  512    // subjects per image
#define NDET  1024   // subjects + objects
#define NCLS  30     // labels 0..29
#define KSLOT 30     // 15 subject + 15 object output slots
#define BCAP  96     // max active boxes per (image,class); mean ~27

#pragma clang fp contract(off)

typedef unsigned long long u64;

// ---------------- Kernel 1: bucketize + per-image box max ------------------
// (verbatim from the verified R2 kernel)
__global__ __launch_bounds__(512) void bucket_kernel(
    const float* __restrict__ sb, const float* __restrict__ ss,
    const int*   __restrict__ sl,
    const float* __restrict__ ob, const float* __restrict__ os,
    const int*   __restrict__ ol,
    float* __restrict__ pmax, int* __restrict__ cnts,
    u64* __restrict__ bkeys, float4* __restrict__ bboxes)
{
    const int b = blockIdx.x, t = threadIdx.x;
    const int lane = t & 63, w = t >> 6;
    __shared__ int   lcnt[NCLS];
    __shared__ float wred[8];

    if (t < NCLS) lcnt[t] = 0;

    // one coalesced load round: box+score+label for subject t and object t
    float4 bxs = *(const float4*)(sb + (size_t)(b * NSUB + t) * 4);
    float4 bxo = *(const float4*)(ob + (size_t)(b * NSUB + t) * 4);
    float scs = ss[b * NSUB + t];  int lbs = sl[b * NSUB + t];
    float sco = os[b * NSUB + t];  int lbo = ol[b * NSUB + t];

    // per-image max (exact; fmax associative)
    float m = fmaxf(fmaxf(fmaxf(bxs.x, bxs.y), fmaxf(bxs.z, bxs.w)),
                    fmaxf(fmaxf(bxo.x, bxo.y), fmaxf(bxo.z, bxo.w)));
    for (int off = 32; off; off >>= 1) m = fmaxf(m, __shfl_xor(m, off));
    if (lane == 0) wred[w] = m;
    __syncthreads();                       // also publishes lcnt init
    if (t == 0) {
        float mm = wred[0];
        for (int i = 1; i < 8; ++i) mm = fmaxf(mm, wred[i]);
        pmax[b] = mm;
    }

    // bucket active detections by class; write key+box straight to ws
    if (scs >= 0.2f) {                     // active = score >= SCORE_THRESH
        int pos = atomicAdd(&lcnt[lbs], 1);
        if (pos < BCAP) {
            size_t s = ((size_t)b * NCLS + lbs) * BCAP + pos;
            bkeys[s]  = ((u64)__float_as_uint(scs) << 32) | (u64)(1023 - t);
            bboxes[s] = bxs;
        }
    }
    if (sco >= 0.2f) {
        int pos = atomicAdd(&lcnt[lbo], 1);
        if (pos < BCAP) {
            size_t s = ((size_t)b * NCLS + lbo) * BCAP + pos;
            bkeys[s]  = ((u64)__float_as_uint(sco) << 32) | (u64)(1023 - (512 + t));
            bboxes[s] = bxo;
        }
    }
    __syncthreads();
    if (t < NCLS) {
        int c = lcnt[t];
        cnts[b * NCLS + t] = (c < BCAP) ? c : BCAP;
    }
}

// ------- Kernel 2: per-(class,image) single-wave greedy NMS ----------------
// Same dataflow as verified R2. IoU/sort arithmetic verbatim. ONLY change:
// the greedy resolve now iterates over KEPT boxes (ffs on an undecided mask,
// one ballot per kept box) instead of one dependent ballot per candidate.
// Kept-set identical: the lowest undecided lane is kept (all earlier kept
// already removed their victims); suppression propagates only from kept.
__global__ __launch_bounds__(64) void nms_class_kernel(
    const float* __restrict__ pmax, const int* __restrict__ cnts,
    const u64* __restrict__ bkeys, const float4* __restrict__ bboxes,
    u64* __restrict__ subk, u64* __restrict__ objk,
    float4* __restrict__ subb, float4* __restrict__ objb)
{
#pragma clang fp contract(off)
    const int c    = blockIdx.x;      // class 0..29
    const int b    = blockIdx.y;      // image
    const int lane = threadIdx.x;

    __shared__ u64    keyarr[BCAP];
    __shared__ u64    skey[BCAP];
    __shared__ float4 bxs4[BCAP];

    const size_t base = (size_t)b * NCLS + c;

    // ---- speculative parallel loads (masked by cnt below; garbage safe) ----
    u64    K1 = bkeys[base * BCAP + lane];
    float4 B1 = bboxes[base * BCAP + lane];
    u64 K2 = 0; float4 B2 = make_float4(0.f, 0.f, 0.f, 0.f);
    if (lane < BCAP - 64) {
        K2 = bkeys[base * BCAP + 64 + lane];
        B2 = bboxes[base * BCAP + 64 + lane];
    }
    const int cnt = cnts[base];                      // pre-clamped to BCAP
    float pv = pmax[lane & 31];                      // 32 per-image partials
    for (int off = 32; off; off >>= 1) pv = fmaxf(pv, __shfl_xor(pv, off));
    const float mco  = pv + 1.0f;                    // (max_coord + 1.0)
    const float offc = (float)c * mco;

    keyarr[lane] = K1;
    if (lane < BCAP - 64) keyarr[64 + lane] = K2;
    __threadfence_block();                           // in-wave LDS RAW

    // ---- rank-sort desc by unique key; scatter key AND box by rank ----
    {
        int r = 0;
        for (int l = 0; l < cnt; ++l) r += (keyarr[l] > K1) ? 1 : 0;
        if (lane < cnt) { skey[r] = K1; bxs4[r] = B1; }
    }
    if (cnt > 64) {                                  // rare second chunk
        int e = 64 + lane;
        int r = 0;
        for (int l = 0; l < cnt; ++l) r += (keyarr[l] > K2) ? 1 : 0;
        if (e < cnt) { skey[r] = K2; bxs4[r] = B2; }
    }
    __threadfence_block();

    // ---- sorted entries now in LDS ----
    const int  lim1  = (cnt < 64) ? cnt : 64;
    const bool have1 = (lane < lim1);
    u64 SK1 = have1 ? skey[lane] : 0;
    int idx1 = 1023 - (int)(unsigned)(SK1 & 0xffffffffull);
    float4 bj1 = have1 ? bxs4[lane] : make_float4(0.f, 0.f, 0.f, 0.f);
    const bool have2 = (64 + lane) < cnt;
    u64 SK2 = 0; int idx2 = 0; float4 bj2 = make_float4(0.f, 0.f, 0.f, 0.f);
    if (cnt > 64) {
        SK2 = have2 ? skey[64 + lane] : 0;
        idx2 = 1023 - (int)(unsigned)(SK2 & 0xffffffffull);
        if (have2) bj2 = bxs4[64 + lane];
    }

    // ---- chunk A: overlap masks (verbatim arithmetic) ----
    float j0 = bj1.x + offc, j1 = bj1.y + offc;
    float j2v = bj1.z + offc, j3 = bj1.w + offc;
    float aj = (j2v - j0) * (j3 - j1);
    u64 ov = 0;
    for (int l = 0; l < lim1; ++l) {
        float4 bl = bxs4[l];
        float i0 = bl.x + offc, i1 = bl.y + offc;
        float i2 = bl.z + offc, i3 = bl.w + offc;
        float ai = (i2 - i0) * (i3 - i1);
        if (have1 && l < lane) {
            float ltx = fmaxf(i0, j0), lty = fmaxf(i1, j1);
            float rbx = fminf(i2, j2v), rby = fminf(i3, j3);
            float wx = fmaxf(rbx - ltx, 0.0f), wy = fmaxf(rby - lty, 0.0f);
            float inter = wx * wy;
            float iou = inter / ((ai + aj) - inter);
            if (iou > 0.5f) ov |= (1ull << l);
        }
    }
    // ---- fast greedy resolve: one ballot per KEPT box ----
    u64 keptm = 0;
    {
        u64 undec = __ballot(have1);
        while (undec) {
            int l = (int)__ffsll((unsigned long long)undec) - 1;  // kept
            keptm |= (1ull << l);
            u64 supby = __ballot(((ov >> l) & 1ull) != 0ull);
            undec &= ~(supby | (1ull << l));
        }
    }
    const bool kept1 = have1 && ((keptm >> lane) & 1ull);
    const u64 keptA = __ballot(kept1);

    // ---- chunk B (rare): entries 64..cnt-1 ----
    bool kept2 = false;
    if (cnt > 64) {
        float k0 = bj2.x + offc, k1 = bj2.y + offc;
        float k2 = bj2.z + offc, k3 = bj2.w + offc;
        float ak = (k2 - k0) * (k3 - k1);
        bool sup2 = !have2;
        u64 ka = keptA;                              // vs kept chunk-A only
        while (ka) {
            int l = (int)__ffsll((unsigned long long)ka) - 1;
            ka &= ka - 1ull;
            float4 bl = bxs4[l];
            float i0 = bl.x + offc, i1 = bl.y + offc;
            float i2 = bl.z + offc, i3 = bl.w + offc;
            float ai = (i2 - i0) * (i3 - i1);
            if (!sup2) {
                float ltx = fmaxf(i0, k0), lty = fmaxf(i1, k1);
                float rbx = fminf(i2, k2), rby = fminf(i3, k3);
                float wx = fmaxf(rbx - ltx, 0.0f), wy = fmaxf(rby - lty, 0.0f);
                float inter = wx * wy;
                float iou = inter / ((ai + ak) - inter);
                if (iou > 0.5f) sup2 = true;
            }
        }
        u64 ov2 = 0;
        const int lim2 = cnt - 64;
        for (int l = 0; l < lim2; ++l) {
            float4 bl = bxs4[64 + l];
            float i0 = bl.x + offc, i1 = bl.y + offc;
            float i2 = bl.z + offc, i3 = bl.w + offc;
            float ai = (i2 - i0) * (i3 - i1);
            if (have2 && l < lane) {
                float ltx = fmaxf(i0, k0), lty = fmaxf(i1, k1);
                float rbx = fminf(i2, k2), rby = fminf(i3, k3);
                float wx = fmaxf(rbx - ltx, 0.0f), wy = fmaxf(rby - lty, 0.0f);
                float inter = wx * wy;
                float iou = inter / ((ai + ak) - inter);
                if (iou > 0.5f) ov2 |= (1ull << l);
            }
        }
        // fast resolve within chunk B (pre-suppressed lanes excluded: they
        // are never kept and never propagate — matches the serial loop)
        u64 keptm2 = 0;
        u64 undec2 = __ballot(have2 && !sup2);
        while (undec2) {
            int l = (int)__ffsll((unsigned long long)undec2) - 1;
            keptm2 |= (1ull << l);
            u64 supby = __ballot(((ov2 >> l) & 1ull) != 0ull);
            undec2 &= ~(supby | (1ull << l));
        }
        kept2 = have2 && !sup2 && ((keptm2 >> lane) & 1ull);
    }

    // ---- write first <=15 kept subject / object (key, box) for this class --
    const bool s1 = kept1 && (idx1 < NSUB), o1 = kept1 && (idx1 >= NSUB);
    const bool s2 = kept2 && (idx2 < NSUB), o2 = kept2 && (idx2 >= NSUB);
    const u64 mS1 = __ballot(s1), mS2 = __ballot(s2);
    const u64 mO1 = __ballot(o1), mO2 = __ballot(o2);
    const u64 ltm = (1ull << lane) - 1ull;
    u64*    subp = subk + base * 15;   float4* sbbp = subb + base * 15;
    u64*    objp = objk + base * 15;   float4* obbp = objb + base * 15;
    if (s1) { int p = (int)__popcll(mS1 & ltm); if (p < 15) { subp[p] = SK1; sbbp[p] = bj1; } }
    if (s2) { int p = (int)__popcll(mS1) + (int)__popcll(mS2 & ltm); if (p < 15) { subp[p] = SK2; sbbp[p] = bj2; } }
    if (o1) { int p = (int)__popcll(mO1 & ltm); if (p < 15) { objp[p] = SK1; obbp[p] = bj1; } }
    if (o2) { int p = (int)__popcll(mO1) + (int)__popcll(mO2 & ltm); if (p < 15) { objp[p] = SK2; obbp[p] = bj2; } }
    int tS = (int)(__popcll(mS1) + __popcll(mS2)); if (tS > 15) tS = 15;
    int tO = (int)(__popcll(mO1) + __popcll(mO2)); if (tO > 15) tO = 15;
    if (lane >= tS && lane < 15) subp[lane] = 0;   // key 0 = empty slot
    if (lane >= tO && lane < 15) objp[lane] = 0;   // (tail boxes never read)
}

// ------- Kernel 3: per-(image,side) top-15 via PARALLEL RANK ---------------
// 512 threads, one kept-slot each. Compact nonzero keys to LDS (order-free:
// rank is computed from values, so output is deterministic). Each valid
// thread computes rank = #{greater keys}; keys are unique (idx low word) so
// ranks are a dense permutation 0..nv-1: rank<15 writes output slot `rank`
// directly. Threads [min(nv,15), 15) write the empty pattern. Replaces 15
// serial argmax rounds (~5000 dependent cycles) with one ~nv-iteration
// broadcast LDS loop.
__global__ __launch_bounds__(512) void select_kernel(
    const u64* __restrict__ subk, const u64* __restrict__ objk,
    const float4* __restrict__ subb, const float4* __restrict__ objb,
    float* __restrict__ out)
{
    const int b    = blockIdx.x;
    const int side = blockIdx.y;          // 0 = subjects, 1 = objects
    const int t    = threadIdx.x;
    const int N    = NCLS * 15;           // 450 slots

    float* outB = out;                    // [32][30][4]
    float* outS = out + BQ * KSLOT * 4;   // 3840
    float* outL = outS + BQ * KSLOT;      // 4800
    float* outN = outL + BQ * KSLOT;      // 5760
    float* outV = outN + BQ;              // 5792

    const u64*    src  = (side ? objk : subk) + (size_t)b * N;
    const float4* srcb = (side ? objb : subb) + (size_t)b * N;

    __shared__ u64 ckey[N + 64];          // compacted keys
    __shared__ int cntv;

    if (t == 0) cntv = 0;
    __syncthreads();

    u64 k = (t < N) ? src[t] : 0;         // coalesced; key 0 = empty slot
    int pos = -1;
    if (k != 0) pos = atomicAdd(&cntv, 1);
    if (pos >= 0) ckey[pos] = k;
    __syncthreads();
    const int nv  = cntv;                 // # valid kept entries this side
    const int nvc = (nv < 15) ? nv : 15;

    if (pos >= 0) {
        int rank = 0;
        for (int l = 0; l < nv; ++l) rank += (ckey[l] > k) ? 1 : 0;  // broadcast
        if (rank < 15) {
            int p = b * KSLOT + (side ? (15 + rank) : rank);
            float4 bx = srcb[t];          // one parallel hop, 15 winners
            *(float4*)(outB + (size_t)p * 4) = bx;
            outS[p] = __uint_as_float((unsigned)(k >> 32));   // exact score
            outL[p] = (float)(t / 15);    // label = bucket class
            outV[p] = 1.0f;
        }
    }
    if (t >= nvc && t < 15) {             // empty slots
        int p = b * KSLOT + (side ? (15 + t) : t);
        *(float4*)(outB + (size_t)p * 4) = make_float4(0.f, 0.f, 0.f, 0.f);
        outS[p] = 0.0f; outL[p] = -1.0f; outV[p] = 0.0f;
    }
    if (side == 0 && t == 0) outN[b] = (float)nvc;  // = min(total_s, 15)
}

extern "C" void kernel_launch(void* const* d_in, const int* in_sizes, int n_in,
                              void* d_out, int out_size, void* d_ws, size_t ws_size,
                              hipStream_t stream) {
    const float* sb = (const float*)d_in[0];
    const float* ss = (const float*)d_in[1];
    const int*   sl = (const int*)d_in[2];
    const float* ob = (const float*)d_in[3];
    const float* os = (const float*)d_in[4];
    const int*   ol = (const int*)d_in[5];

    // ws layout (~2.9 MB total; offsets 256-aligned)
    float*  pmax   = (float*)d_ws;                            // [32]
    int*    cnts   = (int*)((char*)d_ws + 256);               // [32][30]
    u64*    bkeys  = (u64*)((char*)d_ws + 8192);              // [32][30][96]
    float4* bboxes = (float4*)((char*)d_ws + 745472);         // [32][30][96]
    u64*    subk   = (u64*)((char*)d_ws + 2220032);           // [32][30][15]
    u64*    objk   = subk + (size_t)BQ * NCLS * 15;           // [32][30][15]
    float4* subb   = (float4*)((char*)d_ws + 2450432);        // [32][30][15]
    float4* objb   = subb + (size_t)BQ * NCLS * 15;           // [32][30][15]

    bucket_kernel<<<dim3(BQ), dim3(512), 0, stream>>>(
        sb, ss, sl, ob, os, ol, pmax, cnts, bkeys, bboxes);
    nms_class_kernel<<<dim3(NCLS, BQ), dim3(64), 0, stream>>>(
        pmax, cnts, bkeys, bboxes, subk, objk, subb, objb);
    select_kernel<<<dim3(BQ, 2), dim3(512), 0, stream>>>(
        subk, objk, subb, objb, (float*)d_out);
}